// Round 1
// 61.798 us; speedup vs baseline: 1.0033x; 1.0033x over previous
//
#include <hip/hip_runtime.h>
#include <math.h>

// Math collapse (unchanged from v1): softmax_j(sx[b,i] + sk[j] + b0) ==
// softmax_j(sk[j]) by shift-invariance, so attn is identical for every (b,i)
// and out[b,i,:] = sum_j softmax(sk)_j * value[j,:] is ONE 3-vector broadcast
// to all 32*512 rows. x and b are mathematically dead inputs.
//
// v2 changes vs v1 (61.6-62.0 us harness-verified):
//  - thread t owns CONTIGUOUS rows j in [8t, 8t+8): its 24 key floats (96 B)
//    load as 6 float4 (global_load_dwordx4), same for value -> 12 vector
//    loads/thread instead of 48 scalar loads (4x fewer memory instructions,
//    shorter latency chain).
//  - grid 192x256 = 49152 threads = exactly one output float per thread
//    (75% of the 256 CUs instead of 25%).
//  - __expf instead of expf (absmax headroom is enormous: v1 measured 0.0).

__global__ __launch_bounds__(256) void attn_collapsed_v2(
    const float* __restrict__ key,    // (2048, 3)
    const float* __restrict__ value,  // (2048, 3)
    const float* __restrict__ W,      // (1, 6): wx[0:3], wk[3:6]
    float* __restrict__ out)          // (32, 512, 3) flat = 49152 floats
{
    const int tid  = threadIdx.x;          // 0..255
    const int wave = tid >> 6;             // 4 waves of 64
    const int lane = tid & 63;

    const float wk0 = W[3], wk1 = W[4], wk2 = W[5];

    // --- vectorized load: thread t reads key/value floats [24t, 24t+24) ---
    // key base is hipMalloc'd (256B-aligned); 24 floats = 6 float4 per thread.
    const float4* __restrict__ k4 = (const float4*)key;
    const float4* __restrict__ v4 = (const float4*)value;
    float kf[24], vf[24];
#pragma unroll
    for (int q = 0; q < 6; ++q) {
        const float4 a = k4[tid * 6 + q];
        kf[4 * q + 0] = a.x; kf[4 * q + 1] = a.y;
        kf[4 * q + 2] = a.z; kf[4 * q + 3] = a.w;
        const float4 b = v4[tid * 6 + q];
        vf[4 * q + 0] = b.x; vf[4 * q + 1] = b.y;
        vf[4 * q + 2] = b.z; vf[4 * q + 3] = b.w;
    }

    // --- scores sk[r] = key[8t+r] . wk, 8 rows per thread ---
    float sk[8];
    float vmax = -3.4e38f;
#pragma unroll
    for (int r = 0; r < 8; ++r) {
        const float s = fmaf(kf[3 * r + 0], wk0,
                        fmaf(kf[3 * r + 1], wk1, kf[3 * r + 2] * wk2));
        sk[r] = s;
        vmax  = fmaxf(vmax, s);
    }

    // --- block max: 64-lane butterfly, then 4-wave LDS combine ---
#pragma unroll
    for (int m = 32; m >= 1; m >>= 1)
        vmax = fmaxf(vmax, __shfl_xor(vmax, m, 64));
    __shared__ float smax[4];
    if (lane == 0) smax[wave] = vmax;
    __syncthreads();
    const float bmax = fmaxf(fmaxf(smax[0], smax[1]), fmaxf(smax[2], smax[3]));

    // --- exp, partition function, weighted value sums ---
    float z = 0.f, a0 = 0.f, a1 = 0.f, a2 = 0.f;
#pragma unroll
    for (int r = 0; r < 8; ++r) {
        const float e = __expf(sk[r] - bmax);
        z += e;
        a0 = fmaf(e, vf[3 * r + 0], a0);
        a1 = fmaf(e, vf[3 * r + 1], a1);
        a2 = fmaf(e, vf[3 * r + 2], a2);
    }
#pragma unroll
    for (int m = 32; m >= 1; m >>= 1) {
        z  += __shfl_xor(z,  m, 64);
        a0 += __shfl_xor(a0, m, 64);
        a1 += __shfl_xor(a1, m, 64);
        a2 += __shfl_xor(a2, m, 64);
    }
    __shared__ float ssum[4][4];
    if (lane == 0) {
        ssum[wave][0] = z;  ssum[wave][1] = a0;
        ssum[wave][2] = a1; ssum[wave][3] = a2;
    }
    __syncthreads();
    z  = ssum[0][0] + ssum[1][0] + ssum[2][0] + ssum[3][0];
    a0 = ssum[0][1] + ssum[1][1] + ssum[2][1] + ssum[3][1];
    a1 = ssum[0][2] + ssum[1][2] + ssum[2][2] + ssum[3][2];
    a2 = ssum[0][3] + ssum[1][3] + ssum[2][3] + ssum[3][3];

    const float inv = 1.0f / z;
    const float v0 = a0 * inv, v1 = a1 * inv, v2 = a2 * inv;

    // --- one coalesced float per thread ---
    const int gi = blockIdx.x * 256 + tid;   // 0..49151
    const int d  = gi % 3;                   // compiler magic-mul, no div
    out[gi] = (d == 0) ? v0 : ((d == 1) ? v1 : v2);
}

extern "C" void kernel_launch(void* const* d_in, const int* in_sizes, int n_in,
                              void* d_out, int out_size, void* d_ws, size_t ws_size,
                              hipStream_t stream) {
    // setup_inputs order: x(0, unused), key(1), value(2), W(3), b(4, unused)
    const float* key   = (const float*)d_in[1];
    const float* value = (const float*)d_in[2];
    const float* W     = (const float*)d_in[3];
    float* out = (float*)d_out;

    // 192 blocks * 256 threads = 49152 threads = out_size floats
    attn_collapsed_v2<<<dim3(192), dim3(256), 0, stream>>>(key, value, W, out);
}